// Round 1
// baseline (115.815 us; speedup 1.0000x reference)
//
#include <hip/hip_runtime.h>
#include <hip/hip_bf16.h>
#include <stdint.h>

// cheb_conv_with_Att_static: out[b,t,v,c] = relu( sum_{k,f} theta[k,f,c] *
//     sum_u cheb[k,u,v]*Att[b,u,v]*x[b,t,u,f] )
// B=8 T=12 V=2048 F=16 K=3 C=64
#define B_  8
#define T_  12
#define V_  2048
#define F_  16
#define K_  3
#define C_  64
#define N_  192   // T*F

typedef _Float16 f16;
typedef _Float16 half4v __attribute__((ext_vector_type(4)));
typedef _Float16 half8v __attribute__((ext_vector_type(8)));
typedef float    f32x4  __attribute__((ext_vector_type(4)));
typedef float    f32x16 __attribute__((ext_vector_type(16)));
typedef unsigned int u32;

// ---------------------------------------------------------------------------
// Kernel 1: XT[b][n=t*16+f][u] = (f16) x[b][t][u][f]   (u becomes contiguous)
// grid = 96*4 blocks (b,t,uchunk), 256 threads
// ---------------------------------------------------------------------------
__global__ __launch_bounds__(256) void prep_xt(const float* __restrict__ x,
                                               f16* __restrict__ XT) {
  int bid = blockIdx.x;
  int bt = bid >> 2, uc = bid & 3;
  int b = bt / T_, t = bt % T_;
  __shared__ float tile[64][17];
  int r  = threadIdx.x >> 2, fq = threadIdx.x & 3;   // load mapping
  int f  = threadIdx.x >> 4, uq = threadIdx.x & 15;  // store mapping
  for (int u0 = uc * 512; u0 < uc * 512 + 512; u0 += 64) {
    f32x4 v = *(const f32x4*)(x + ((size_t)(b * T_ + t) * V_ + u0 + r) * F_ + fq * 4);
    tile[r][fq * 4 + 0] = v[0];
    tile[r][fq * 4 + 1] = v[1];
    tile[r][fq * 4 + 2] = v[2];
    tile[r][fq * 4 + 3] = v[3];
    __syncthreads();
    half4v h;
    h[0] = (f16)tile[uq * 4 + 0][f];
    h[1] = (f16)tile[uq * 4 + 1][f];
    h[2] = (f16)tile[uq * 4 + 2][f];
    h[3] = (f16)tile[uq * 4 + 3][f];
    *(half4v*)(XT + (size_t)(b * N_ + t * F_ + f) * V_ + u0 + uq * 4) = h;
    __syncthreads();
  }
}

// ---------------------------------------------------------------------------
// Kernel 2: per (k,b): rhs[v,(t,f)] = sum_u (cheb[k,u,v]*Att[b,u,v]) * x[b,t,u,f]
// BM=64 (v), BN=192 (all t,f), BK=64.  4 waves, wave tile 32x96 (32x32x16 f16 MFMA).
// A tile (S^T, [v][u] K-contig) built on the fly: coalesced fp32 loads of cheb/Att,
// product, f16, transposed ds_write with (v&7)<<4 XOR swizzle (b128 reads conflict-free).
// B tile staged with global_load_lds (16B) from XT, source pre-swizzled (n&7)<<4.
// Output rhs[b][t][v][k*16+f] (f16): kf-contiguous rows for kernel 3's A-fragments.
// grid = 3*8*32 = 768 blocks
// ---------------------------------------------------------------------------
__global__ __launch_bounds__(256) void gemm_kbv(const float* __restrict__ Att,
                                                const float* __restrict__ cheb,
                                                const f16* __restrict__ XT,
                                                f16* __restrict__ rhs) {
  const int vt = blockIdx.x & 31;
  const int kb = blockIdx.x >> 5;
  const int k = kb >> 3, b = kb & 7;
  const int vbase = vt * 64;

  __shared__ char smem[32768];
  char* Ab = smem;           // 8 KB : [64 v][64 u] f16, 128B rows, swz ^((v&7)<<4)
  char* Bb = smem + 8192;    // 24 KB: [192 n][64 u] f16, 128B rows, swz ^((n&7)<<4)

  const int tid = threadIdx.x;
  const int wave = tid >> 6, lane = tid & 63;
  const int wm = wave >> 1, wn = wave & 1;           // 2x2 wave grid
  const int vsub = (tid & 15) * 4, usub = (tid >> 4) * 4;

  f32x16 acc[3];
  acc[0] = 0; acc[1] = 0; acc[2] = 0;

  for (int u0 = 0; u0 < V_; u0 += 64) {
    __syncthreads();
    // ---- stage A: 4x4 subtile per thread, register transpose ----
    const float* cp = cheb + ((size_t)k * V_ + u0 + usub) * V_ + vbase + vsub;
    const float* ap = Att  + ((size_t)b * V_ + u0 + usub) * V_ + vbase + vsub;
    f32x4 p[4];
#pragma unroll
    for (int i = 0; i < 4; ++i) {
      f32x4 cv = *(const f32x4*)(cp + (size_t)i * V_);
      f32x4 av = *(const f32x4*)(ap + (size_t)i * V_);
      p[i] = cv * av;
    }
#pragma unroll
    for (int j = 0; j < 4; ++j) {
      int vrow = vsub + j;
      half4v h;
      h[0] = (f16)p[0][j]; h[1] = (f16)p[1][j];
      h[2] = (f16)p[2][j]; h[3] = (f16)p[3][j];
      *(half4v*)(Ab + vrow * 128 + ((usub * 2) ^ ((vrow & 7) << 4))) = h;
    }
    // ---- stage B: 24 x 1KB wave-issues of global_load_lds, src pre-swizzled ----
#pragma unroll
    for (int e = 0; e < 6; ++e) {
      int slot = wave * 6 + e;                 // 0..23
      int n = slot * 8 + (lane >> 3);          // LDS row this lane fills
      int cp2 = lane & 7;                      // 16B chunk within row (linear dest)
      int c = cp2 ^ (n & 7);                   // source chunk (inverse swizzle)
      const f16* src = XT + (size_t)(b * N_ + n) * V_ + u0 + c * 8;
      __builtin_amdgcn_global_load_lds((const __attribute__((address_space(1))) u32*)src,
                                       (__attribute__((address_space(3))) u32*)(Bb + slot * 1024),
                                       16, 0, 0);
    }
    __syncthreads();   // compiler drains vmcnt+lgkmcnt before barrier
    // ---- compute: 4 k-frags x (1 A-frag, 3 B-frags) ----
#pragma unroll
    for (int ks = 0; ks < 4; ++ks) {
      int koff = ks * 32 + (lane >> 5) * 16;
      int vrow = wm * 32 + (lane & 31);
      half8v a = *(const half8v*)(Ab + vrow * 128 + (koff ^ ((vrow & 7) << 4)));
#pragma unroll
      for (int nf = 0; nf < 3; ++nf) {
        int nrow = wn * 96 + nf * 32 + (lane & 31);
        half8v bv = *(const half8v*)(Bb + nrow * 128 + (koff ^ ((nrow & 7) << 4)));
        acc[nf] = __builtin_amdgcn_mfma_f32_32x32x16_f16(a, bv, acc[nf], 0, 0, 0);
      }
    }
  }

  // ---- epilogue: scatter acc -> rhs[b][t][v][k*16+f] (f16) ----
#pragma unroll
  for (int nf = 0; nf < 3; ++nf) {
    int n = wn * 96 + nf * 32 + (lane & 31);
    int t = n >> 4, fi = n & 15;
#pragma unroll
    for (int r = 0; r < 16; ++r) {
      int v = vbase + wm * 32 + (r & 3) + 8 * (r >> 2) + 4 * (lane >> 5);
      rhs[((size_t)(b * T_ + t) * V_ + v) * 48 + k * 16 + fi] = (f16)acc[nf][r];
    }
  }
}

// ---------------------------------------------------------------------------
// Kernel 3: out[row, c] = relu( sum_{kf=0..47} rhs[row][kf] * theta[kf][c] )
// rows = b*T*V = 196608.  A-frags straight from global (rows kf-contiguous),
// B-frags (theta, f16) built in registers.  grid = 1536 blocks x 4 waves x 32 rows.
// ---------------------------------------------------------------------------
__global__ __launch_bounds__(256) void epi(const f16* __restrict__ rhs,
                                           const float* __restrict__ theta,
                                           float* __restrict__ out) {
  int wave = threadIdx.x >> 6, lane = threadIdx.x & 63;
  int row0 = blockIdx.x * 128 + wave * 32;
  int cl = lane & 31, kh = (lane >> 5) * 8;

  half8v bf[2][3];
#pragma unroll
  for (int nf = 0; nf < 2; ++nf)
#pragma unroll
    for (int ks = 0; ks < 3; ++ks) {
      half8v hb;
#pragma unroll
      for (int j = 0; j < 8; ++j)
        hb[j] = (f16)theta[(size_t)(ks * 16 + kh + j) * C_ + nf * 32 + cl];
      bf[nf][ks] = hb;
    }

  f32x16 acc0 = 0, acc1 = 0;
#pragma unroll
  for (int ks = 0; ks < 3; ++ks) {
    half8v a = *(const half8v*)(rhs + (size_t)(row0 + cl) * 48 + ks * 16 + kh);
    acc0 = __builtin_amdgcn_mfma_f32_32x32x16_f16(a, bf[0][ks], acc0, 0, 0, 0);
    acc1 = __builtin_amdgcn_mfma_f32_32x32x16_f16(a, bf[1][ks], acc1, 0, 0, 0);
  }
#pragma unroll
  for (int r = 0; r < 16; ++r) {
    int row = row0 + (r & 3) + 8 * (r >> 2) + 4 * (lane >> 5);
    out[(size_t)row * C_ + cl]      = fmaxf(acc0[r], 0.f);
    out[(size_t)row * C_ + 32 + cl] = fmaxf(acc1[r], 0.f);
  }
}

// ---------------------------------------------------------------------------
extern "C" void kernel_launch(void* const* d_in, const int* in_sizes, int n_in,
                              void* d_out, int out_size, void* d_ws, size_t ws_size,
                              hipStream_t stream) {
  const float* x     = (const float*)d_in[0];   // (8,12,2048,16)
  const float* Att   = (const float*)d_in[1];   // (8,2048,2048)
  const float* cheb  = (const float*)d_in[2];   // (3,2048,2048)
  const float* theta = (const float*)d_in[3];   // (3,16,64)
  float* out = (float*)d_out;                   // (8,12,2048,64) fp32

  // workspace: XT f16 (6.29 MB) + rhs f16 (18.87 MB) = 25.2 MB
  f16* XT  = (f16*)d_ws;
  f16* rhs = (f16*)((char*)d_ws + (size_t)B_ * N_ * V_ * sizeof(f16));

  prep_xt<<<B_ * T_ * 4, 256, 0, stream>>>(x, XT);
  gemm_kbv<<<K_ * B_ * 32, 256, 0, stream>>>(Att, cheb, XT, rhs);
  epi<<<(B_ * T_ * V_) / 128, 256, 0, stream>>>(rhs, theta, out);
}